// Round 7
// baseline (27.115 us; speedup 1.0000x reference)
//
#include <hip/hip_runtime.h>
#include <math.h>

// Problem constants (match reference)
constexpr int   T_DIM = 4096;
constexpr int   NC    = 10;
constexpr int   K1COL = 512;             // cols per K1 block (eighth-row)
constexpr int   NQ    = T_DIM / K1COL;   // 8 chunks per row
constexpr int   K1THR = 256;             // 4 waves; grid 2048 -> 8 blocks/CU = 32 waves/CU
constexpr int   K2THR = 1024;            // 16 waves, one block per row
constexpr int   K2WAVE = K2THR / 64;
constexpr int   PSTRIDE = 16;

constexpr float EPS_C   = 0.2f;
constexpr float ALPHA_C = 0.5f;
constexpr float GAMMA_C = 1e-4f;
constexpr float MU_C    = 8e-4f;

// ws layout (floats):
//   Smean[B*T] | Amean[B*T] | cmax[B*NQ] | cmin[B*NQ] | part1[B*NQ][8] | part2[B][16]

// ---------------------------------------------------------------------------
// K1: streaming. 32 waves/CU. NO atomics. Writes means + chunk max/min +
// theta-independent raw sums (v0,v1,v4,v5,v6,v7) per chunk.
// ---------------------------------------------------------------------------
__global__ __launch_bounds__(K1THR) void mbs_k1(
    const float* __restrict__ scores,
    const float* __restrict__ attw,
    const int*   __restrict__ seqlen,
    float*       __restrict__ ws,
    int B)
{
    float* Smean = ws;
    float* Amean = ws + (size_t)B * T_DIM;
    float* cmax  = Amean + (size_t)B * T_DIM;
    float* cmin  = cmax + (size_t)B * NQ;
    float* part1 = cmin + (size_t)B * NQ;

    const int bid  = blockIdx.x;
    const int row  = bid >> 3;
    const int q    = bid & 7;
    const int tid  = threadIdx.x;
    const int lane = tid & 63;
    const int w    = tid >> 6;
    const int slen = seqlen[row];
    const int c0   = q * K1COL;

    if (c0 >= slen) {                    // fully-masked chunk
        if (tid == 0) {
            cmax[row * NQ + q] = -INFINITY;
            cmin[row * NQ + q] =  INFINITY;
            float* p = part1 + (size_t)bid * 8;
#pragma unroll
            for (int k = 0; k < 6; ++k) p[k] = 0.f;
        }
        return;
    }

    const int  gc     = c0 + tid * 2;    // this thread's 2 cols
    const bool active = gc < slen;

    __shared__ float ssl[K1COL + 1];     // mean slab incl. prev col at [0]
    __shared__ float asl[K1COL + 1];

    float2 s2 = make_float2(0.f, 0.f);
    float2 a2 = make_float2(0.f, 0.f);
    if (active) {
        const float* sp = scores + (size_t)row * NC * T_DIM + gc;
        const float* ap = attw   + (size_t)row * NC * T_DIM + gc;
#pragma unroll
        for (int c = 0; c < NC; ++c) {
            const float2 v = *reinterpret_cast<const float2*>(sp + (size_t)c * T_DIM);
            s2.x += v.x; s2.y += v.y;
        }
#pragma unroll
        for (int c = 0; c < NC; ++c) {
            const float2 v = *reinterpret_cast<const float2*>(ap + (size_t)c * T_DIM);
            a2.x += v.x; a2.y += v.y;
        }
        const float invNC = 1.0f / (float)NC;
        s2.x *= invNC; s2.y *= invNC;
        a2.x *= invNC; a2.y *= invNC;
        *reinterpret_cast<float2*>(Smean + (size_t)row * T_DIM + gc) = s2;
        *reinterpret_cast<float2*>(Amean + (size_t)row * T_DIM + gc) = a2;
        ssl[1 + 2 * tid] = s2.x; ssl[2 + 2 * tid] = s2.y;
        asl[1 + 2 * tid] = a2.x; asl[2 + 2 * tid] = a2.y;
    }
    if (tid == 0) {                      // prev-col mean for boundary pair
        float sp_ = 0.f, ap_ = 0.f;
        if (q > 0) {
            const float* sb = scores + (size_t)row * NC * T_DIM + (c0 - 1);
            const float* ab = attw   + (size_t)row * NC * T_DIM + (c0 - 1);
#pragma unroll
            for (int c = 0; c < NC; ++c) {
                sp_ += sb[(size_t)c * T_DIM];
                ap_ += ab[(size_t)c * T_DIM];
            }
            sp_ *= 0.1f; ap_ *= 0.1f;
        }
        ssl[0] = sp_; asl[0] = ap_;
    }
    __syncthreads();

    // theta-independent terms
    const bool pos  = row < (B >> 1);
    const bool isLG = (row == (B >> 1) - 1) || (row == B - 1);
    float mx = -INFINITY, mn = INFINITY;
    float v0 = 0.f, v1 = 0.f, v4 = 0.f, v5 = 0.f, v6 = 0.f, v7 = 0.f;
    if (active) {
        const float sarr[2] = {s2.x, s2.y};
        const float aarr[2] = {a2.x, a2.y};
#pragma unroll
        for (int j = 0; j < 2; ++j) {
            if (gc + j < slen) {
                const float s  = sarr[j];
                const float a  = aarr[j];
                const float sa = s * a;
                mx = fmaxf(mx, a);
                mn = fminf(mn, a);
                if (pos) {
                    v0 += fmaxf(__logf(s),  -100.0f);
                    v1 += fmaxf(__logf(sa), -100.0f);
                    v4 += fabsf(a);
                    if (isLG) v5 += (a - s) * (a - s);
                } else {
                    v0 += fmaxf(__logf(1.0f - s),  -100.0f);
                    v1 += fmaxf(__logf(1.0f - sa), -100.0f);
                    if (isLG) v5 += a * a;
                }
                v7 += s + sa;
            }
        }
    }
    // smoothness: pair p = (col c0-1+p, col c0+p), p in [0,512)
#pragma unroll
    for (int j = 0; j < 2; ++j) {
        const int p  = 2 * tid + j;
        const int lc = c0 - 1 + p;
        if (lc >= 0 && lc < slen - 1) {
            const float ds  = ssl[p] - ssl[p + 1];
            const float dsa = ssl[p] * asl[p] - ssl[p + 1] * asl[p + 1];
            v6 += ds * ds + dsa * dsa;
        }
    }

    // block reduce (4 waves)
    float vals[8] = {mx, mn, v0, v1, v4, v5, v6, v7};
#pragma unroll
    for (int off = 32; off; off >>= 1) {
        vals[0] = fmaxf(vals[0], __shfl_down(vals[0], off, 64));
        vals[1] = fminf(vals[1], __shfl_down(vals[1], off, 64));
#pragma unroll
        for (int k = 2; k < 8; ++k)
            vals[k] += __shfl_down(vals[k], off, 64);
    }
    __shared__ float red[4][8];
    if (lane == 0)
#pragma unroll
        for (int k = 0; k < 8; ++k) red[w][k] = vals[k];
    __syncthreads();
    if (tid == 0) {
        float t[8];
#pragma unroll
        for (int k = 0; k < 8; ++k) t[k] = red[0][k];
#pragma unroll
        for (int w2 = 1; w2 < 4; ++w2) {
            t[0] = fmaxf(t[0], red[w2][0]);
            t[1] = fminf(t[1], red[w2][1]);
#pragma unroll
            for (int k = 2; k < 8; ++k) t[k] += red[w2][k];
        }
        cmax[row * NQ + q] = t[0];
        cmin[row * NQ + q] = t[1];
        float* p = part1 + (size_t)bid * 8;
        p[0] = t[2]; p[1] = t[3]; p[2] = t[4];
        p[3] = t[5]; p[4] = t[6]; p[5] = t[7];
    }
}

// ---------------------------------------------------------------------------
// K2: one block per row. theta + sup-BCE from cached means; combine part1;
// write scaled per-row 9-vector. Plain stores only.
// ---------------------------------------------------------------------------
__global__ __launch_bounds__(K2THR) void mbs_k2(
    const int*   __restrict__ seqlen,
    float*       __restrict__ ws,
    int B)
{
    const float* Smean = ws;
    const float* Amean = ws + (size_t)B * T_DIM;
    const float* cmax  = Amean + (size_t)B * T_DIM;
    const float* cmin  = cmax + (size_t)B * NQ;
    const float* part1 = cmin + (size_t)B * NQ;
    float*       part2 = const_cast<float*>(part1) + (size_t)B * NQ * 8;

    const int row  = blockIdx.x;
    const int tid  = threadIdx.x;
    const int lane = tid & 63;
    const int w    = tid >> 6;
    const int slen = seqlen[row];
    const bool pos = row < (B >> 1);
    const int t0   = tid * 4;
    const bool active = t0 < slen;

    float mx = -INFINITY, mn = INFINITY;
#pragma unroll
    for (int c = 0; c < NQ; ++c) {
        mx = fmaxf(mx, cmax[row * NQ + c]);
        mn = fminf(mn, cmin[row * NQ + c]);
    }
    const float theta = (mx - mn) * EPS_C + mn;

    float v2 = 0.f, v3 = 0.f;
    if (active) {
        const float4 s4 = *reinterpret_cast<const float4*>(Smean + (size_t)row * T_DIM + t0);
        const float4 a4 = *reinterpret_cast<const float4*>(Amean + (size_t)row * T_DIM + t0);
        const float sarr[4] = {s4.x, s4.y, s4.z, s4.w};
        const float aarr[4] = {a4.x, a4.y, a4.z, a4.w};
#pragma unroll
        for (int j = 0; j < 4; ++j) {
            if (t0 + j < slen) {
                const float s  = sarr[j];
                const float a  = aarr[j];
                const float sa = s * a;
                const bool sup = a < theta;
                if (pos) {
                    v2 += sup ? fmaxf(__logf(s),  -100.0f) : -100.0f;
                    v3 += sup ? fmaxf(__logf(sa), -100.0f) : -100.0f;
                } else if (sup) {
                    v2 += fmaxf(__logf(1.0f - s),  -100.0f);
                    v3 += fmaxf(__logf(1.0f - sa), -100.0f);
                }
            }
        }
    }

    float vals[2] = {v2, v3};
#pragma unroll
    for (int off = 32; off; off >>= 1) {
        vals[0] += __shfl_down(vals[0], off, 64);
        vals[1] += __shfl_down(vals[1], off, 64);
    }
    __shared__ float red[K2WAVE][2];
    if (lane == 0) { red[w][0] = vals[0]; red[w][1] = vals[1]; }
    __syncthreads();

    if (tid == 0) {
        float t2 = 0.f, t3 = 0.f;
#pragma unroll
        for (int w2 = 0; w2 < K2WAVE; ++w2) { t2 += red[w2][0]; t3 += red[w2][1]; }

        float r[6] = {0.f, 0.f, 0.f, 0.f, 0.f, 0.f};  // v0,v1,v4,v5,v6,v7
#pragma unroll
        for (int c = 0; c < NQ; ++c) {
            const float* p1 = part1 + (size_t)(row * NQ + c) * 8;
#pragma unroll
            for (int k = 0; k < 6; ++k) r[k] += p1[k];
        }

        const float inv_slen = 1.0f / (float)slen;
        const float invB2    = 2.0f / (float)B;   // 1/128
        float* p = part2 + (size_t)row * PSTRIDE;
        p[0] = ALPHA_C          * (-r[0] * inv_slen) * invB2;
        p[1] = ALPHA_C          * (-r[1] * inv_slen) * invB2;
        p[2] = (1.0f - ALPHA_C) * (-t2   * inv_slen) * invB2;
        p[3] = (1.0f - ALPHA_C) * (-t3   * inv_slen) * invB2;
        p[4] = pos ? (GAMMA_C * r[2] * invB2) : 0.0f;
        p[5] = (row == B - 1)        ? r[3] * inv_slen : 0.0f;  // LG_0
        p[6] = (row == (B >> 1) - 1) ? r[3] * inv_slen : 0.0f;  // LG_1
        p[7] = MU_C * r[4] * invB2;
        p[8] = r[5] * invB2;
    }
}

__global__ __launch_bounds__(64) void mbs_k3(
    const float* __restrict__ part2,
    float*       __restrict__ out,
    int B)
{
    float acc[9];
#pragma unroll
    for (int k = 0; k < 9; ++k) acc[k] = 0.f;
    for (int r = (int)threadIdx.x; r < B; r += 64) {
        const float* p = part2 + (size_t)r * PSTRIDE;
#pragma unroll
        for (int k = 0; k < 9; ++k) acc[k] += p[k];
    }
#pragma unroll
    for (int k = 0; k < 9; ++k)
#pragma unroll
        for (int off = 32; off; off >>= 1)
            acc[k] += __shfl_down(acc[k], off, 64);
    if (threadIdx.x == 0)
#pragma unroll
        for (int k = 0; k < 9; ++k) out[k] = acc[k];
}

extern "C" void kernel_launch(void* const* d_in, const int* in_sizes, int n_in,
                              void* d_out, int out_size, void* d_ws, size_t ws_size,
                              hipStream_t stream) {
    const float* scores = (const float*)d_in[0];
    const float* attw   = (const float*)d_in[1];
    // d_in[2] = label (unused: reference splits by fixed B/2)
    const int*   seqlen = (const int*)d_in[3];
    const int B = in_sizes[2];

    float* ws    = (float*)d_ws;
    float* part2 = ws + (size_t)B * T_DIM * 2 + (size_t)B * NQ * 2 + (size_t)B * NQ * 8;

    mbs_k1<<<dim3(B * NQ), dim3(K1THR), 0, stream>>>(scores, attw, seqlen, ws, B);
    mbs_k2<<<dim3(B), dim3(K2THR), 0, stream>>>(seqlen, ws, B);
    mbs_k3<<<dim3(1), dim3(64), 0, stream>>>(part2, (float*)d_out, B);
}

// Round 8
// 26.699 us; speedup vs baseline: 1.0156x; 1.0156x over previous
//
#include <hip/hip_runtime.h>
#include <math.h>

// Problem constants (match reference)
constexpr int   T_DIM = 4096;
constexpr int   NC    = 10;
constexpr int   WIN   = 512;             // cols per K1 window
constexpr int   NQ    = T_DIM / WIN;     // 8 windows per row
constexpr int   K2THR = 1024;
constexpr int   K2WAVE = K2THR / 64;
constexpr int   PSTRIDE = 16;

constexpr float EPS_C   = 0.2f;
constexpr float ALPHA_C = 0.5f;
constexpr float GAMMA_C = 1e-4f;
constexpr float MU_C    = 8e-4f;

// ws layout (floats): Smean[B*T] | Amean[B*T] | cmax[B*NQ] | cmin[B*NQ] | part2[B*16]

__device__ __forceinline__ void gl_lds16(const float* g, float* l) {
    // async global->LDS DMA, 16B/lane: LDS dest = wave-uniform base + lane*16
    __builtin_amdgcn_global_load_lds(
        (const __attribute__((address_space(1))) void*)g,
        (__attribute__((address_space(3))) void*)l, 16, 0, 0);
}

// ---------------------------------------------------------------------------
// K1: LDS-DMA staged channel means (bypasses the L1/MSHR return path that
// capped every VGPR-load variant at ~2.2 TB/s). 40KB LDS -> 4 blocks/CU.
// ---------------------------------------------------------------------------
__global__ __launch_bounds__(256) void mbs_k1(
    const float* __restrict__ scores,
    const float* __restrict__ attw,
    const int*   __restrict__ seqlen,
    float*       __restrict__ ws,
    int B)
{
    float* Smean = ws;
    float* Amean = ws + (size_t)B * T_DIM;
    float* cmax  = Amean + (size_t)B * T_DIM;
    float* cmin  = cmax + (size_t)B * NQ;

    __shared__ float sl[NC][WIN];   // 20 KB
    __shared__ float al[NC][WIN];   // 20 KB

    const int bid  = blockIdx.x;
    const int row  = bid >> 3;
    const int win  = bid & 7;
    const int tid  = threadIdx.x;
    const int lane = tid & 63;
    const int w    = tid >> 6;
    const int slen = seqlen[row];
    const int c0   = win * WIN;

    if (c0 >= slen) {                       // fully-masked window
        if (tid == 0) {
            cmax[row * NQ + win] = -INFINITY;
            cmin[row * NQ + win] =  INFINITY;
        }
        return;
    }

    // ---- stage 40 x 1KB pieces via global_load_lds (10 per wave) ----
    const size_t rowbase = (size_t)row * NC * T_DIM;
    const bool   hi      = (c0 + 256) < slen;    // second half-window needed?
#pragma unroll
    for (int i = 0; i < 10; ++i) {
        const int piece = w * 10 + i;       // wave-uniform
        const int half  = piece / 20;       // 0 = scores, 1 = attw
        const int rem   = piece % 20;
        const int c     = rem >> 1;
        const int part  = rem & 1;
        if (part == 0 || hi) {
            const float* g = (half ? attw : scores)
                           + rowbase + (size_t)c * T_DIM + c0 + part * 256 + lane * 4;
            float* l = (half ? &al[0][0] : &sl[0][0]) + c * WIN + part * 256;
            gl_lds16(g, l);
        }
    }
    __syncthreads();                        // drains vmcnt -> staged data visible

    // ---- means for 2 cols/thread, write to ws ----
    const size_t rowm = (size_t)row * T_DIM;
    const int  cc  = 2 * tid;
    const int  col = c0 + cc;
    const bool act = col < slen;
    float amx = -INFINITY, amn = INFINITY;
    if (act) {
        float s0 = 0.f, s1 = 0.f, a0 = 0.f, a1 = 0.f;
#pragma unroll
        for (int c = 0; c < NC; ++c) {
            const float2 sv = *reinterpret_cast<const float2*>(&sl[c][cc]);
            const float2 av = *reinterpret_cast<const float2*>(&al[c][cc]);
            s0 += sv.x; s1 += sv.y;
            a0 += av.x; a1 += av.y;
        }
        const float2 sm = make_float2(s0 * 0.1f, s1 * 0.1f);
        const float2 am = make_float2(a0 * 0.1f, a1 * 0.1f);
        *reinterpret_cast<float2*>(Smean + rowm + col) = sm;
        *reinterpret_cast<float2*>(Amean + rowm + col) = am;
        amx = am.x; amn = am.x;
        if (col + 1 < slen) { amx = fmaxf(amx, am.y); amn = fminf(amn, am.y); }
    }

    // ---- window max/min of A-mean ----
#pragma unroll
    for (int off = 32; off; off >>= 1) {
        amx = fmaxf(amx, __shfl_down(amx, off, 64));
        amn = fminf(amn, __shfl_down(amn, off, 64));
    }
    __syncthreads();                        // all sl/al reads done; reuse sl
    if (lane == 0) { sl[0][w] = amx; sl[0][4 + w] = amn; }
    __syncthreads();
    if (tid == 0) {
        const float mx = fmaxf(fmaxf(sl[0][0], sl[0][1]), fmaxf(sl[0][2], sl[0][3]));
        const float mn = fminf(fminf(sl[0][4], sl[0][5]), fminf(sl[0][6], sl[0][7]));
        cmax[row * NQ + win] = mx;
        cmin[row * NQ + win] = mn;
    }
}

// ---------------------------------------------------------------------------
// K2: one block per row; theta from window max/mins; all nine reductions from
// the (L2/L3-hot) means; plain stores of scaled per-row partials.
// ---------------------------------------------------------------------------
__global__ __launch_bounds__(K2THR) void mbs_k2(
    const int*   __restrict__ seqlen,
    const float* __restrict__ ws,
    float*       __restrict__ part2,
    int B)
{
    const float* Smean = ws;
    const float* Amean = ws + (size_t)B * T_DIM;
    const float* cmax  = Amean + (size_t)B * T_DIM;
    const float* cmin  = cmax + (size_t)B * NQ;

    __shared__ float s_lds[T_DIM];
    __shared__ float a_lds[T_DIM];
    __shared__ float red_sum[K2WAVE][8];

    const int b    = blockIdx.x;
    const int tid  = threadIdx.x;
    const int lane = tid & 63;
    const int wid  = tid >> 6;
    const int slen = seqlen[b];
    const bool pos = b < (B >> 1);
    const bool isLG = (b == (B >> 1) - 1) || (b == B - 1);
    const int t0   = tid * 4;
    const bool active = t0 < slen;

    float mx = -INFINITY, mn = INFINITY;
#pragma unroll
    for (int c = 0; c < NQ; ++c) {
        mx = fmaxf(mx, cmax[b * NQ + c]);
        mn = fminf(mn, cmin[b * NQ + c]);
    }
    const float theta = (mx - mn) * EPS_C + mn;

    float4 s4 = make_float4(0.f, 0.f, 0.f, 0.f);
    float4 a4 = make_float4(0.f, 0.f, 0.f, 0.f);
    if (active) {
        s4 = *reinterpret_cast<const float4*>(Smean + (size_t)b * T_DIM + t0);
        a4 = *reinterpret_cast<const float4*>(Amean + (size_t)b * T_DIM + t0);
        reinterpret_cast<float4*>(s_lds)[tid] = s4;
        reinterpret_cast<float4*>(a_lds)[tid] = a4;
    }
    __syncthreads();

    const float sarr[4] = {s4.x, s4.y, s4.z, s4.w};
    const float aarr[4] = {a4.x, a4.y, a4.z, a4.w};

    float v0 = 0.f, v1 = 0.f, v2 = 0.f, v3 = 0.f,
          v4 = 0.f, v5 = 0.f, v6 = 0.f, v7 = 0.f;
    if (active) {
#pragma unroll
        for (int j = 0; j < 4; ++j) {
            const int t = t0 + j;
            const float s  = sarr[j];
            const float a  = aarr[j];
            const float sa = s * a;
            if (t < slen) {
                const bool sup = a < theta;
                if (pos) {
                    const float ls  = fmaxf(__logf(s),  -100.0f);
                    const float lsa = fmaxf(__logf(sa), -100.0f);
                    v0 += ls;
                    v1 += lsa;
                    v2 += sup ? ls  : -100.0f;   // log(0) clamped
                    v3 += sup ? lsa : -100.0f;
                    v4 += fabsf(a);
                    if (isLG) v5 += (a - s) * (a - s);
                } else {
                    const float ls  = fmaxf(__logf(1.0f - s),  -100.0f);
                    const float lsa = fmaxf(__logf(1.0f - sa), -100.0f);
                    v0 += ls;
                    v1 += lsa;
                    if (sup) { v2 += ls; v3 += lsa; }  // !sup -> log(1)=0
                    if (isLG) v5 += a * a;
                }
                v7 += s + sa;
            }
            if (t < slen - 1) {
                const float s2 = (j < 3) ? sarr[j + 1] : s_lds[t + 1];
                const float a2 = (j < 3) ? aarr[j + 1] : a_lds[t + 1];
                const float ds  = s  - s2;
                const float dsa = sa - s2 * a2;
                v6 += ds * ds + dsa * dsa;
            }
        }
    }

    float vals[8] = {v0, v1, v2, v3, v4, v5, v6, v7};
#pragma unroll
    for (int k = 0; k < 8; ++k)
#pragma unroll
        for (int off = 32; off; off >>= 1)
            vals[k] += __shfl_down(vals[k], off, 64);
    if (lane == 0)
#pragma unroll
        for (int k = 0; k < 8; ++k) red_sum[wid][k] = vals[k];
    __syncthreads();

    if (tid == 0) {
        float tot[8];
#pragma unroll
        for (int k = 0; k < 8; ++k) tot[k] = 0.f;
        for (int w2 = 0; w2 < K2WAVE; ++w2)
#pragma unroll
            for (int k = 0; k < 8; ++k) tot[k] += red_sum[w2][k];

        const float inv_slen = 1.0f / (float)slen;
        const float invB2    = 2.0f / (float)B;   // 1/128
        float* p = part2 + (size_t)b * PSTRIDE;
        p[0] = ALPHA_C          * (-tot[0] * inv_slen) * invB2;
        p[1] = ALPHA_C          * (-tot[1] * inv_slen) * invB2;
        p[2] = (1.0f - ALPHA_C) * (-tot[2] * inv_slen) * invB2;
        p[3] = (1.0f - ALPHA_C) * (-tot[3] * inv_slen) * invB2;
        p[4] = pos ? (GAMMA_C * tot[4] * invB2) : 0.0f;
        p[5] = (b == B - 1)        ? tot[5] * inv_slen : 0.0f;  // LG_0
        p[6] = (b == (B >> 1) - 1) ? tot[5] * inv_slen : 0.0f;  // LG_1
        p[7] = MU_C * tot[6] * invB2;
        p[8] = tot[7] * invB2;
    }
}

__global__ __launch_bounds__(64) void mbs_k3(
    const float* __restrict__ part2,
    float*       __restrict__ out,
    int B)
{
    float acc[9];
#pragma unroll
    for (int k = 0; k < 9; ++k) acc[k] = 0.f;
    for (int r = (int)threadIdx.x; r < B; r += 64) {
        const float* p = part2 + (size_t)r * PSTRIDE;
#pragma unroll
        for (int k = 0; k < 9; ++k) acc[k] += p[k];
    }
#pragma unroll
    for (int k = 0; k < 9; ++k)
#pragma unroll
        for (int off = 32; off; off >>= 1)
            acc[k] += __shfl_down(acc[k], off, 64);
    if (threadIdx.x == 0)
#pragma unroll
        for (int k = 0; k < 9; ++k) out[k] = acc[k];
}

extern "C" void kernel_launch(void* const* d_in, const int* in_sizes, int n_in,
                              void* d_out, int out_size, void* d_ws, size_t ws_size,
                              hipStream_t stream) {
    const float* scores = (const float*)d_in[0];
    const float* attw   = (const float*)d_in[1];
    // d_in[2] = label (unused: reference splits by fixed B/2)
    const int*   seqlen = (const int*)d_in[3];
    const int B = in_sizes[2];

    float* ws    = (float*)d_ws;
    float* part2 = ws + (size_t)B * T_DIM * 2 + (size_t)B * NQ * 2;

    mbs_k1<<<dim3(B * NQ), dim3(256), 0, stream>>>(scores, attw, seqlen, ws, B);
    mbs_k2<<<dim3(B), dim3(K2THR), 0, stream>>>(seqlen, ws, part2, B);
    mbs_k3<<<dim3(1), dim3(64), 0, stream>>>(part2, (float*)d_out, B);
}

// Round 10
// 18.722 us; speedup vs baseline: 1.4483x; 1.4261x over previous
//
#include <hip/hip_runtime.h>
#include <math.h>

// Problem constants (match reference)
constexpr int   T_DIM = 4096;
constexpr int   NC    = 10;
constexpr int   NTHR  = 1024;          // 16 waves/block, one block per batch row
constexpr int   NWAVE = NTHR / 64;
constexpr int   PSTRIDE = 16;          // floats per partial-row in d_ws

constexpr float EPS_C   = 0.2f;
constexpr float ALPHA_C = 0.5f;
constexpr float GAMMA_C = 1e-4f;
constexpr float MU_C    = 8e-4f;

typedef float vfloat4 __attribute__((ext_vector_type(4)));  // nt-load-compatible

__global__ __launch_bounds__(NTHR) void mbs_pass1(
    const float* __restrict__ scores,
    const float* __restrict__ attw,
    const int*   __restrict__ seqlen,
    float*       __restrict__ part,    // [B][PSTRIDE] per-block contributions
    int B)
{
    __shared__ float s_lds[T_DIM];
    __shared__ float a_lds[T_DIM];
    __shared__ float red_mx[NWAVE];
    __shared__ float red_mn[NWAVE];
    __shared__ float red_sum[NWAVE][8];
    __shared__ float sh_theta;

    const int tid  = threadIdx.x;
    const int lane = tid & 63;
    const int wid  = tid >> 6;
    const int b    = blockIdx.x;
    const int slen = seqlen[b];
    const bool pos = b < (B >> 1);
    const int t0   = tid * 4;
    const bool active = t0 < slen;     // elements t>=slen are never used by ANY term

    // ---------- pass 1: channel mean; read-once streams via NON-TEMPORAL
    // loads (bypass L1 allocation: 20KB/wave x 16 waves thrashes the 32KB L1,
    // adding L1 miss-handling to every line's latency on the MSHR-capped path).
    vfloat4 s4 = {0.f, 0.f, 0.f, 0.f};
    vfloat4 a4 = {0.f, 0.f, 0.f, 0.f};
    if (active) {
        const float* sp = scores + (size_t)b * NC * T_DIM + t0;
        const float* ap = attw   + (size_t)b * NC * T_DIM + t0;
#pragma unroll
        for (int h = 0; h < 2; ++h) {
            vfloat4 sv[5], av[5];
#pragma unroll
            for (int c = 0; c < 5; ++c)
                sv[c] = __builtin_nontemporal_load(
                    reinterpret_cast<const vfloat4*>(sp + (size_t)(h * 5 + c) * T_DIM));
#pragma unroll
            for (int c = 0; c < 5; ++c)
                av[c] = __builtin_nontemporal_load(
                    reinterpret_cast<const vfloat4*>(ap + (size_t)(h * 5 + c) * T_DIM));
#pragma unroll
            for (int c = 0; c < 5; ++c) {
                s4 += sv[c];
                a4 += av[c];
            }
        }
        const float invNC = 1.0f / (float)NC;
        s4 *= invNC;
        a4 *= invNC;

        *reinterpret_cast<vfloat4*>(&s_lds[t0]) = s4;
        *reinterpret_cast<vfloat4*>(&a_lds[t0]) = a4;
    }

    const float sarr[4] = {s4.x, s4.y, s4.z, s4.w};
    const float aarr[4] = {a4.x, a4.y, a4.z, a4.w};

    float amax = -INFINITY, amin = INFINITY;
    if (active) {
#pragma unroll
        for (int j = 0; j < 4; ++j) {
            if (t0 + j < slen) {
                amax = fmaxf(amax, aarr[j]);
                amin = fminf(amin, aarr[j]);
            }
        }
    }
#pragma unroll
    for (int off = 32; off; off >>= 1) {
        amax = fmaxf(amax, __shfl_down(amax, off, 64));
        amin = fminf(amin, __shfl_down(amin, off, 64));
    }
    if (lane == 0) { red_mx[wid] = amax; red_mn[wid] = amin; }
    __syncthreads();   // also publishes s_lds/a_lds for pass-2 neighbor reads
    if (tid == 0) {
        float mx = red_mx[0], mn = red_mn[0];
#pragma unroll
        for (int w = 1; w < NWAVE; ++w) {
            mx = fmaxf(mx, red_mx[w]);
            mn = fminf(mn, red_mn[w]);
        }
        sh_theta = (mx - mn) * EPS_C + mn;
    }
    __syncthreads();
    const float theta = sh_theta;

    // ---------- pass 2: all reductions from registers (+LDS neighbor) ----------
    // v0=log(S) bce, v1=log(SA) bce, v2=sup bce(S), v3=sup bce(SA),
    // v4=sum|A| (pos rows), v5=LG sum (rows B/2-1, B-1), v6=smooth, v7=spread
    float v0 = 0.f, v1 = 0.f, v2 = 0.f, v3 = 0.f,
          v4 = 0.f, v5 = 0.f, v6 = 0.f, v7 = 0.f;
    const bool isLG = (b == (B >> 1) - 1) || (b == B - 1);

    if (active) {
#pragma unroll
        for (int j = 0; j < 4; ++j) {
            const int t   = t0 + j;
            const float s  = sarr[j];
            const float a  = aarr[j];
            const float sa = s * a;
            if (t < slen) {
                const bool sup = a < theta;
                if (pos) {
                    const float ls  = fmaxf(__logf(s),  -100.0f);
                    const float lsa = fmaxf(__logf(sa), -100.0f);
                    v0 += ls;
                    v1 += lsa;
                    v2 += sup ? ls  : -100.0f;   // log(0) clamped
                    v3 += sup ? lsa : -100.0f;
                    v4 += fabsf(a);
                    if (isLG) v5 += (a - s) * (a - s);
                } else {
                    const float ls  = fmaxf(__logf(1.0f - s),  -100.0f);
                    const float lsa = fmaxf(__logf(1.0f - sa), -100.0f);
                    v0 += ls;
                    v1 += lsa;
                    if (sup) { v2 += ls; v3 += lsa; }  // !sup -> log(1-0)=0
                    if (isLG) v5 += a * a;
                }
                v7 += s + sa;
            }
            if (t < slen - 1) {   // t+1 < slen, owner thread of t+1 was active
                const float s2 = (j < 3) ? sarr[j + 1] : s_lds[t + 1];
                const float a2 = (j < 3) ? aarr[j + 1] : a_lds[t + 1];
                const float ds  = s  - s2;
                const float dsa = sa - s2 * a2;
                v6 += ds * ds + dsa * dsa;
            }
        }
    }

    // ---------- block reduce 8 sums ----------
    float vals[8] = {v0, v1, v2, v3, v4, v5, v6, v7};
#pragma unroll
    for (int k = 0; k < 8; ++k) {
#pragma unroll
        for (int off = 32; off; off >>= 1)
            vals[k] += __shfl_down(vals[k], off, 64);
    }
    if (lane == 0) {
#pragma unroll
        for (int k = 0; k < 8; ++k) red_sum[wid][k] = vals[k];
    }
    __syncthreads();

    if (tid == 0) {
        float tot[8];
#pragma unroll
        for (int k = 0; k < 8; ++k) tot[k] = 0.f;
        for (int w = 0; w < NWAVE; ++w)
#pragma unroll
            for (int k = 0; k < 8; ++k) tot[k] += red_sum[w][k];

        const float inv_slen = 1.0f / (float)slen;
        const float invB2    = 2.0f / (float)B;   // 1/128

        float* p = part + (size_t)b * PSTRIDE;
        p[0] = ALPHA_C          * (-tot[0] * inv_slen) * invB2;
        p[1] = ALPHA_C          * (-tot[1] * inv_slen) * invB2;
        p[2] = (1.0f - ALPHA_C) * (-tot[2] * inv_slen) * invB2;
        p[3] = (1.0f - ALPHA_C) * (-tot[3] * inv_slen) * invB2;
        p[4] = pos ? (GAMMA_C * tot[4] * invB2) : 0.0f;
        p[5] = (b == B - 1)        ? tot[5] * inv_slen : 0.0f;  // LG_0 (row B-1)
        p[6] = (b == (B >> 1) - 1) ? tot[5] * inv_slen : 0.0f;  // LG_1 (row B/2-1)
        p[7] = MU_C * tot[6] * invB2;
        p[8] = tot[7] * invB2;
    }
}

__global__ __launch_bounds__(64) void mbs_pass2(
    const float* __restrict__ part,
    float*       __restrict__ out,
    int B)
{
    float acc[9];
#pragma unroll
    for (int k = 0; k < 9; ++k) acc[k] = 0.f;
    for (int r = (int)threadIdx.x; r < B; r += 64) {
        const float* p = part + (size_t)r * PSTRIDE;
#pragma unroll
        for (int k = 0; k < 9; ++k) acc[k] += p[k];
    }
#pragma unroll
    for (int k = 0; k < 9; ++k) {
#pragma unroll
        for (int off = 32; off; off >>= 1)
            acc[k] += __shfl_down(acc[k], off, 64);
    }
    if (threadIdx.x == 0) {
#pragma unroll
        for (int k = 0; k < 9; ++k) out[k] = acc[k];
    }
}

extern "C" void kernel_launch(void* const* d_in, const int* in_sizes, int n_in,
                              void* d_out, int out_size, void* d_ws, size_t ws_size,
                              hipStream_t stream) {
    const float* scores = (const float*)d_in[0];
    const float* attw   = (const float*)d_in[1];
    // d_in[2] = label (unused: reference splits by fixed B/2)
    const int*   seqlen = (const int*)d_in[3];
    const int B = in_sizes[2];

    float* part = (float*)d_ws;   // B * PSTRIDE floats, rewritten every launch

    mbs_pass1<<<dim3(B), dim3(NTHR), 0, stream>>>(scores, attw, seqlen, part, B);
    mbs_pass2<<<dim3(1), dim3(64), 0, stream>>>(part, (float*)d_out, B);
}